// Round 4
// baseline (3743.276 us; speedup 1.0000x reference)
//
#include <hip/hip_runtime.h>

typedef unsigned short u16;
typedef short short8 __attribute__((ext_vector_type(8)));
typedef float f32x4 __attribute__((ext_vector_type(4)));
typedef unsigned int u32x2 __attribute__((ext_vector_type(2)));
typedef unsigned short u16x4 __attribute__((ext_vector_type(4)));

#define Bsz 32
#define Tsz 512
#define Dsz 1024
#define Usz 1024
#define Gsz 4096   // 4*U

// ---- bf16 helpers (manual RNE) ----
static __device__ __forceinline__ u16 f2bf(float f) {
    unsigned int u = __float_as_uint(f);
    unsigned int lsb = (u >> 16) & 1u;
    u += 0x7fffu + lsb;
    return (u16)(u >> 16);
}
static __device__ __forceinline__ float bf2f(u16 b) {
    return __uint_as_float(((unsigned int)b) << 16);
}

// =====================================================================
// Pack kernels: MFMA-fragment-ordered bf16 buffers.
// A-frag (16x16x32): lane L holds A[m = mt*16 + (L&15)][k = kb*32 + (L>>4)*8 + j]
// B-frag:            lane L holds B[k = kb*32 + (L>>4)*8 + j][n = nt*16 + (L&15)]
// Flat: buf[((tile*32 + kb)*64 + L)*8 + j] -> lane-contiguous 16B chunks.
// =====================================================================

__global__ __launch_bounds__(256) void pack_a(const float* __restrict__ x, u16* __restrict__ Af) {
    size_t tid = (size_t)blockIdx.x * 256 + threadIdx.x;
    int L = (int)(tid & 63);
    size_t mtkb = tid >> 6;
    int kb = (int)(mtkb & 31);
    int mt = (int)(mtkb >> 5);
    int m  = mt * 16 + (L & 15);
    int d0 = kb * 32 + (L >> 4) * 8;
    const float* src = x + (size_t)m * Dsz + d0;
    short8 v;
#pragma unroll
    for (int j = 0; j < 8; ++j) v[j] = (short)f2bf(src[j]);
    *(short8*)(Af + tid * 8) = v;
}

__global__ __launch_bounds__(256) void pack_b(const float* __restrict__ W, u16* __restrict__ Bf) {
    size_t tid = (size_t)blockIdx.x * 256 + threadIdx.x;
    int L = (int)(tid & 63);
    size_t ntkb = tid >> 6;
    int kb = (int)(ntkb & 31);
    int nt = (int)(ntkb >> 5);
    int n  = nt * 16 + (L & 15);
    int k0 = kb * 32 + (L >> 4) * 8;
    short8 v;
#pragma unroll
    for (int j = 0; j < 8; ++j) v[j] = (short)f2bf(W[(size_t)(k0 + j) * Gsz + n]);
    *(short8*)(Bf + tid * 8) = v;
}

// R -> Rp for the 128-block scan: tile tt = blk*2 + nt (256 tiles).
// Tile-local col c15 -> cc = nt*16 + c15, gate = cc>>3, du = cc&7,
// global col g = gate*1024 + blk*8 + du. Also zeroes 256 barrier flags.
__global__ __launch_bounds__(256) void pack_r(const float* __restrict__ R, u16* __restrict__ Rp,
                                              unsigned* __restrict__ flags) {
    if (blockIdx.x == 0) flags[threadIdx.x] = 0;
    size_t tid = (size_t)blockIdx.x * 256 + threadIdx.x;
    int L = (int)(tid & 63);
    int kb = (int)((tid >> 6) & 31);
    int tt = (int)(tid >> 11);
    int blk = tt >> 1, nt = tt & 1;
    int cc = nt * 16 + (L & 15);
    int gate = cc >> 3, du = cc & 7;
    int g = gate * 1024 + blk * 8 + du;
    int k0 = kb * 32 + (L >> 4) * 8;
    short8 v;
#pragma unroll
    for (int j = 0; j < 8; ++j) v[j] = (short)f2bf(R[(size_t)(k0 + j) * Gsz + g]);
    *(short8*)(Rp + tid * 8) = v;
}

// =====================================================================
// GEMM1: x_proj = X @ W; 128x128 tile, 4 waves. Epilogue writes the
// scan layout: p = blk(128)*32 + du(8)*4 + gate(4)  (128B/block per (t,b)).
// =====================================================================
__global__ __launch_bounds__(256) void gemm1(const u16* __restrict__ Af, const u16* __restrict__ Bf,
                                             float* __restrict__ xpf, u16* __restrict__ xph, int xp32) {
    __shared__ u16 smem[16 * 512];
    int bm = blockIdx.x >> 5;
    int bn = blockIdx.x & 31;
    int tid = threadIdx.x;
    int w = tid >> 6, ln = tid & 63;
    int mw = w & 1, nw = w >> 1;

    f32x4 acc[4][4];
#pragma unroll
    for (int i = 0; i < 4; ++i)
#pragma unroll
        for (int j = 0; j < 4; ++j) acc[i][j] = (f32x4){0.f, 0.f, 0.f, 0.f};

    for (int kb = 0; kb < 32; ++kb) {
        short8 tmp[4];
#pragma unroll
        for (int c2 = 0; c2 < 4; ++c2) {
            int chunk = w * 4 + c2;
            const u16* src = (chunk < 8)
                ? Af + (((size_t)(bm * 8 + chunk) * 32 + kb) * 64 + ln) * 8
                : Bf + (((size_t)(bn * 8 + (chunk - 8)) * 32 + kb) * 64 + ln) * 8;
            tmp[c2] = *(const short8*)src;
        }
#pragma unroll
        for (int c2 = 0; c2 < 4; ++c2) {
            int chunk = w * 4 + c2;
            *(short8*)(smem + chunk * 512 + ln * 8) = tmp[c2];
        }
        __syncthreads();
        short8 av[4], bv[4];
#pragma unroll
        for (int i = 0; i < 4; ++i) av[i] = *(const short8*)(smem + (mw * 4 + i) * 512 + ln * 8);
#pragma unroll
        for (int j = 0; j < 4; ++j) bv[j] = *(const short8*)(smem + (8 + nw * 4 + j) * 512 + ln * 8);
#pragma unroll
        for (int i = 0; i < 4; ++i)
#pragma unroll
            for (int j = 0; j < 4; ++j)
                acc[i][j] = __builtin_amdgcn_mfma_f32_16x16x32_bf16(av[i], bv[j], acc[i][j], 0, 0, 0);
        __syncthreads();
    }

    int quad = ln >> 4, c15 = ln & 15;
#pragma unroll
    for (int i = 0; i < 4; ++i) {
        int mt_g = bm * 8 + mw * 4 + i;
#pragma unroll
        for (int j = 0; j < 4; ++j) {
            int g = (bn * 8 + nw * 4 + j) * 16 + c15;
            int p = ((g & 1023) >> 3) * 32 + (g & 7) * 4 + (g >> 10);
#pragma unroll
            for (int r = 0; r < 4; ++r) {
                int row = mt_g * 16 + quad * 4 + r;
                int bb = row >> 9, tt = row & 511;
                size_t o = ((size_t)tt * Bsz + bb) * Gsz + p;
                if (xp32) xpf[o] = acc[i][j][r];
                else      xph[o] = f2bf(acc[i][j][r]);
            }
        }
    }
}

// =====================================================================
// Scan: 128 blocks x 512 threads (8 waves). Block owns 8 units (32 cols).
// Waves: mt = w&1 (batch half), nt = (w>>1)&1 (N-tile), kh = w>>2 (K-half).
// B-frags in registers (64 VGPR). h staged once per block into LDS in
// fragment order via sc0sc1 loads. Wide 16B h writeback by wave0.
// =====================================================================
__global__ __launch_bounds__(512) void scan_all(const float* __restrict__ xpf,
                                                const u16* __restrict__ xph, int xp32,
                                                const u16* __restrict__ Rp,
                                                const float* __restrict__ bias,
                                                u16* __restrict__ hbf, float* __restrict__ out,
                                                unsigned* __restrict__ flags) {
    __shared__ u16 hlds[64 * 64 * 8];      // 64KB: h in fragment order [frag(64)][lane(64)][8]
    __shared__ float partial[4][64][4];    // 4KB
    __shared__ float proj[32][34];         // 4.25KB (pad 34 -> spread gate reads)
    __shared__ u16 hstage[32][8];          // 512B: bf16 h staging for wide writeback

    int tid = threadIdx.x;
    int blk = blockIdx.x;                  // 0..127
    int w = tid >> 6, ln = tid & 63, quad = ln >> 4, c15 = ln & 15;
    int mt = w & 1, nt = (w >> 1) & 1, kh = w >> 2;
    bool upd = (tid < 256);                // waves 0-3 == kh==0 waves
    int b_row = tid >> 3, du = tid & 7;    // valid for upd threads
    int u_g = blk * 8 + du;

    u16* hb0 = hbf;                        // written at even t
    u16* hb1 = hbf + 32 * 1024;            // written at odd t; zeros for t=0

    // ---- B fragments -> registers (16 x short8 = 64 VGPR) ----
    short8 bfr[16];
    {
        const u16* bB = Rp + (((size_t)(blk * 2 + nt) * 32 + kh * 16) * 64 + ln) * 8;
#pragma unroll
        for (int kk = 0; kk < 16; ++kk)
            bfr[kk] = *(const short8*)(bB + (size_t)kk * 512);
    }

    float bi[4] = {0.f, 0.f, 0.f, 0.f};
    float cs = 0.f, ns = 0.f, ms = 0.f;
    if (upd) {
#pragma unroll
        for (int g = 0; g < 4; ++g) bi[g] = bias[g * 1024 + u_g];
        u16* hp = hb1 + b_row * Usz + u_g;
        unsigned z = 0;
        asm volatile("global_store_short %0, %1, off sc0 sc1" :: "v"(hp), "v"(z) : "memory");
    }
    asm volatile("s_waitcnt vmcnt(0)" ::: "memory");
    __syncthreads();
    if (tid == 0) {
        unsigned* fp = flags + blk;
        unsigned one = 1;
        asm volatile("global_store_dword %0, %1, off sc0 sc1" :: "v"(fp), "v"(one) : "memory");
    }

    for (int t = 0; t < Tsz; ++t) {
        // ---- poll: wave0, 2 flags/lane covers 128 blocks ----
        if (w == 0) {
            const unsigned* fp2 = flags + ln * 2;
            unsigned tgt = (unsigned)(t + 1);
            u32x2 fv;
            do {
                asm volatile("global_load_dwordx2 %0, %1, off sc0 sc1\n\ts_waitcnt vmcnt(0)"
                             : "=v"(fv) : "v"(fp2) : "memory");
            } while (__any((int)(fv[0] < tgt || fv[1] < tgt)));
        }
        __syncthreads();

        // ---- stage h_{t-1} -> LDS in fragment order ----
        // thread (w, ln), iter it: frag f = it*8 + w;
        //   m = (f>>5)*16 + (ln&15), u0 = (f&31)*32 + ((ln>>4)&3)*8
        const u16* rb = (t & 1) ? hb0 : hb1;
        short8 st[8];
#pragma unroll
        for (int it = 0; it < 8; ++it) {
            int f = it * 8 + w;
            int m = (f >> 5) * 16 + (ln & 15);
            int u0 = (f & 31) * 32 + ((ln >> 4) & 3) * 8;
            const u16* gp = rb + m * Usz + u0;
            asm volatile("global_load_dwordx4 %0, %1, off sc0 sc1" : "=v"(st[it]) : "v"(gp));
        }
        // x_proj load (cached; drains with the staging waitcnt, consumed at gates)
        float xv0 = 0.f, xv1 = 0.f, xv2 = 0.f, xv3 = 0.f;
        if (upd) {
            size_t o = ((size_t)t * Bsz + b_row) * Gsz + blk * 32 + du * 4;
            if (xp32) { float4 v4 = *(const float4*)(xpf + o); xv0 = v4.x; xv1 = v4.y; xv2 = v4.z; xv3 = v4.w; }
            else      { u16x4 v = *(const u16x4*)(xph + o); xv0 = bf2f(v[0]); xv1 = bf2f(v[1]); xv2 = bf2f(v[2]); xv3 = bf2f(v[3]); }
        }
        asm volatile("s_waitcnt vmcnt(0)" ::: "memory");
#pragma unroll
        for (int it = 0; it < 8; ++it) {
            int f = it * 8 + w;
            *(short8*)(hlds + ((size_t)f * 64 + ln) * 8) = st[it];
        }
        __syncthreads();

        // ---- MFMA: wave (mt,nt,kh) over its 16 fragments; B in regs ----
        f32x4 acc0 = (f32x4){0.f, 0.f, 0.f, 0.f};
        f32x4 acc1 = (f32x4){0.f, 0.f, 0.f, 0.f};
#pragma unroll
        for (int kk = 0; kk < 16; kk += 2) {
            short8 a0 = *(const short8*)(hlds + (((mt * 32 + kh * 16 + kk) * 64) + ln) * 8);
            short8 a1 = *(const short8*)(hlds + (((mt * 32 + kh * 16 + kk + 1) * 64) + ln) * 8);
            acc0 = __builtin_amdgcn_mfma_f32_16x16x32_bf16(a0, bfr[kk], acc0, 0, 0, 0);
            acc1 = __builtin_amdgcn_mfma_f32_16x16x32_bf16(a1, bfr[kk + 1], acc1, 0, 0, 0);
        }
        f32x4 acc = acc0 + acc1;

        // ---- K-half reduce: kh=1 waves publish, kh=0 waves consume ----
        if (kh == 1) *(f32x4*)(&partial[w - 4][ln][0]) = acc;
        __syncthreads();
        if (kh == 0) {
            f32x4 p = *(const f32x4*)(&partial[w][ln][0]);
#pragma unroll
            for (int r = 0; r < 4; ++r)
                proj[mt * 16 + quad * 4 + r][nt * 16 + c15] = acc[r] + p[r];
        }
        __syncthreads();

        float h = 0.f;
        if (upd) {
            float ip = proj[b_row][du]      + xv0 + bi[0];
            float fp = proj[b_row][8 + du]  + xv1 + bi[1];
            float op = proj[b_row][16 + du] + xv2 + bi[2];
            float zp = proj[b_row][24 + du] + xv3 + bi[3];
            float sf = 1.f / (1.f + __expf(-fp));
            float lf = __logf(sf + 1e-8f);
            float mn = fmaxf(ms + lf, ip);
            float it_ = __expf(ip - mn);
            float ft = __expf(ms + lf - mn);
            float ot = 1.f / (1.f + __expf(-op));
            float zt = tanhf(zp);
            cs = ft * cs + it_ * zt;
            ns = ft * ns + it_;
            ms = mn;
            h = ot * (cs / (ns + 1e-8f));
            hstage[b_row][du] = f2bf(h);
        }
        __syncthreads();

        // ---- wide h writeback + flag: wave0 only (no extra barrier) ----
        if (w == 0) {
            if (ln < 32) {
                short8 hv = *(const short8*)(&hstage[ln][0]);
                u16* hp = ((t & 1) ? hb1 : hb0) + ln * Usz + blk * 8;
                asm volatile("global_store_dwordx4 %0, %1, off sc0 sc1" :: "v"(hp), "v"(hv) : "memory");
            }
            asm volatile("s_waitcnt vmcnt(0)" ::: "memory");
            if (ln == 0) {
                unsigned* fp = flags + blk;
                unsigned val = (unsigned)(t + 2);
                asm volatile("global_store_dword %0, %1, off sc0 sc1" :: "v"(fp), "v"(val) : "memory");
            }
        }
        // ---- out store: off the critical path (after flag) ----
        if (upd)
            out[(size_t)b_row * (Tsz * Usz) + (size_t)t * Usz + u_g] = h;
    }
}

// =====================================================================
extern "C" void kernel_launch(void* const* d_in, const int* in_sizes, int n_in,
                              void* d_out, int out_size, void* d_ws, size_t ws_size,
                              hipStream_t stream) {
    const float* x    = (const float*)d_in[0];
    const float* W    = (const float*)d_in[1];
    const float* R    = (const float*)d_in[2];
    const float* bias = (const float*)d_in[3];
    float* out = (float*)d_out;

    char* ws = (char*)d_ws;
    size_t off = 0;
    u16* Af = (u16*)(ws + off); off += (size_t)16384 * 1024 * 2;  // 32MB
    u16* Bf = (u16*)(ws + off); off += (size_t)1024 * 4096 * 2;   // 8MB
    u16* Rp = (u16*)(ws + off); off += (size_t)1024 * 4096 * 2;   // 8MB
    u16* hbf = (u16*)(ws + off); off += (size_t)1 << 20;          // 1MB (2x64KB used)
    unsigned* flags = (unsigned*)(ws + off); off += 4096;         // 256 flags (128 used)
    size_t xp_need32 = (size_t)16384 * 4096 * 4;                  // 256MB
    int xp32 = (ws_size >= off + xp_need32) ? 1 : 0;
    float* xpf = (float*)(ws + off);
    u16*   xph = (u16*)(ws + off);

    pack_a<<<dim3(8192), dim3(256), 0, stream>>>(x, Af);
    pack_b<<<dim3(2048), dim3(256), 0, stream>>>(W, Bf);
    pack_r<<<dim3(2048), dim3(256), 0, stream>>>(R, Rp, flags);
    gemm1<<<dim3(4096), dim3(256), 0, stream>>>(Af, Bf, xpf, xph, xp32);

    void* args[] = { (void*)&xpf, (void*)&xph, (void*)&xp32, (void*)&Rp,
                     (void*)&bias, (void*)&hbf, (void*)&out, (void*)&flags };
    hipLaunchCooperativeKernel((const void*)scan_all, dim3(128), dim3(512), args, 0, stream);
}